// Round 2
// baseline (262.431 us; speedup 1.0000x reference)
//
#include <hip/hip_runtime.h>

#define NROWS 32768
#define DIM   128
#define KCODES 4096
#define DECAYF 0.8f
#define EPSF 1e-5f
#define COMMITW 0.25f

typedef _Float16 half8 __attribute__((ext_vector_type(8)));
typedef _Float16 half2v __attribute__((ext_vector_type(2)));
typedef float float4v __attribute__((ext_vector_type(4)));

// direct global->LDS copy: lane i's 16B from gsrc(lane-addressed) lands at
// ldsbase + i*16 (HW-fixed linear dest, wave-uniform base)
__device__ inline void stage1k(const _Float16* gsrc, _Float16* ldsbase) {
    __builtin_amdgcn_global_load_lds(
        (const __attribute__((address_space(1))) void*)gsrc,
        (__attribute__((address_space(3))) void*)ldsbase, 16, 0, 0);
}

// ---------------- embed -> staged split planes + e2 ----------------
// R2 estg layout (halves): [chunk][pl][ks][j][q][m15][8]
//   offset = chunk*16384 + (((pl*4+ks)*4 + j)*64 + q*16 + m15)*8 + e
// A wave (fixed j) reading frag (pl,ks) covers lanes (q,m15) -> one
// CONTIGUOUS 1KB ds_read_b128 (conflict-free), and a chunk is one linear
// 32KB block for global_load_lds staging.
__global__ __launch_bounds__(256) void esplit_kernel(const float* __restrict__ embed,
                                                     _Float16* __restrict__ estg,
                                                     float* __restrict__ e2h) {
    int code = blockIdx.x * 4 + (threadIdx.x >> 6);
    int lane = threadIdx.x & 63;
    float2 v = ((const float2*)(embed + (size_t)code * DIM))[lane];
    float s = v.x * v.x + v.y * v.y;
    #pragma unroll
    for (int off = 32; off > 0; off >>= 1) s += __shfl_down(s, off, 64);
    if (lane == 0) e2h[code] = 0.5f * s;

    int d = lane * 2;
    int ks = d >> 5, q = (d >> 3) & 3, e = d & 7;
    _Float16 h0 = (_Float16)v.x, l0 = (_Float16)(v.x - (float)h0);
    _Float16 h1 = (_Float16)v.y, l1 = (_Float16)(v.y - (float)h1);
    int chunk = code >> 6, c6 = code & 63;
    int jj = c6 >> 4, m15c = c6 & 15;
    size_t base = (size_t)chunk * 16384;
    size_t hidx = base + (size_t)(((0 * 4 + ks) * 4 + jj) * 64 + q * 16 + m15c) * 8 + e;
    size_t lidx = base + (size_t)(((1 * 4 + ks) * 4 + jj) * 64 + q * 16 + m15c) * 8 + e;
    *(half2v*)&estg[hidx] = (half2v){h0, h1};
    *(half2v*)&estg[lidx] = (half2v){l0, l1};
}

// ---------------- MFMA argmax: 128 rows/block, 16 waves, LDS-staged -------
// R2 change: B-path. R0/R1 register-streamed B from L2 with 2-4x per-wave
// duplication -> ~28% vmcnt stall, MfmaUtil stuck at 41-46%. Now: each chunk
// (32KB) staged ONCE per block into LDS dbuf via global_load_lds (2 loads
// per thread, issued a full chunk ahead of the barrier that drains them -
// T14), waves ds_read_b128 contiguous 1KB fragments (estg layout above).
// One barrier per chunk; setprio(1) around the MFMA cluster (T5).
__global__ __launch_bounds__(1024, 4) void argmax_kernel(const float* __restrict__ x,
                                                         const _Float16* __restrict__ estg,
                                                         const float* __restrict__ e2h,
                                                         int* __restrict__ ind,
                                                         float* __restrict__ out_ind,
                                                         int* __restrict__ bins,
                                                         float* __restrict__ loss) {
    __shared__ __align__(16) _Float16 bstg[2][16384];   // 2 x 32KB chunk dbuf
    __shared__ float rv[16][32];
    __shared__ int   ri[16][32];
    __shared__ float x2s[128];

    int tid = threadIdx.x;
    int lane = tid & 63;
    int w = tid >> 6;          // 0..15
    int j = w & 3;             // code-tile
    int rh = w >> 2;           // row-quarter 0..3
    int m15 = lane & 15;
    int q = (lane >> 4) & 3;
    int n0 = blockIdx.x * 128;

    // stage chunk 0 early (latency hides under A-load/convert below)
    {
        const _Float16* g0 = estg + (size_t)(w * 2) * 512 + (size_t)lane * 8;
        stage1k(g0, &bstg[0][(w * 2) * 512]);
        stage1k(g0 + 512, &bstg[0][(w * 2 + 1) * 512]);
    }

    // A frags for this wave's 32 rows (rows n0 + rh*32 + rt*16 + m15)
    half8 Ah[2][4], Al[2][4];
    float xsq[2];
    #pragma unroll
    for (int rt = 0; rt < 2; ++rt) {
        xsq[rt] = 0.f;
        #pragma unroll
        for (int ks = 0; ks < 4; ++ks) {
            const float* p = x + (size_t)(n0 + rh * 32 + rt * 16 + m15) * DIM + ks * 32 + q * 8;
            float4 a = *(const float4*)p;
            float4 b = *(const float4*)(p + 4);
            float f[8] = {a.x, a.y, a.z, a.w, b.x, b.y, b.z, b.w};
            half8 H, L;
            #pragma unroll
            for (int e = 0; e < 8; ++e) {
                _Float16 h = (_Float16)f[e];
                H[e] = h;
                L[e] = (_Float16)(f[e] - (float)h);
                xsq[rt] += f[e] * f[e];
            }
            Ah[rt][ks] = H;
            Al[rt][ks] = L;
        }
        xsq[rt] += __shfl_xor(xsq[rt], 16, 64);
        xsq[rt] += __shfl_xor(xsq[rt], 32, 64);
    }
    if (j == 0 && lane < 16) {
        #pragma unroll
        for (int rt = 0; rt < 2; ++rt) x2s[rh * 32 + rt * 16 + m15] = xsq[rt];
    }

    float best[2][4];
    int   bidx[2][4];
    #pragma unroll
    for (int rt = 0; rt < 2; ++rt)
        #pragma unroll
        for (int r = 0; r < 4; ++r) { best[rt][r] = -3.0e38f; bidx[rt][r] = 0; }

    const int cm = j * 16 + m15;
    float e2cur = e2h[cm];

    __syncthreads();   // drains chunk-0 staging (vmcnt 0) + syncs block

    int cur = 0;
    #pragma unroll 1
    for (int ch = 0; ch < 64; ++ch) {
        // issue next-chunk staging NOW; its drain is the barrier at loop end,
        // a full chunk (~2000 cy) away (T14 issue-early / drain-late)
        int chn = (ch + 1 < 64) ? ch + 1 : 0;
        {
            const _Float16* gn = estg + (size_t)chn * 16384 + (size_t)(w * 2) * 512 + (size_t)lane * 8;
            _Float16* db = &bstg[cur ^ 1][(w * 2) * 512];
            stage1k(gn, db);
            stage1k(gn + 512, db + 512);
        }
        float e2n = e2h[chn * 64 + cm];

        // B fragments from LDS: contiguous 1KB per read, conflict-free
        const _Float16* bufc = bstg[cur];
        half8 Bh[4], Bl[4];
        #pragma unroll
        for (int ks = 0; ks < 4; ++ks) {
            Bh[ks] = ((const half8*)(bufc + (size_t)(((0 * 4 + ks) * 4 + j) * 512)))[lane];
            Bl[ks] = ((const half8*)(bufc + (size_t)(((1 * 4 + ks) * 4 + j) * 512)))[lane];
        }

        float4v acc[2];
        #pragma unroll
        for (int rt = 0; rt < 2; ++rt) acc[rt] = (float4v){-e2cur, -e2cur, -e2cur, -e2cur};

        __builtin_amdgcn_s_setprio(1);
        #pragma unroll
        for (int ks = 0; ks < 4; ++ks)
            #pragma unroll
            for (int rt = 0; rt < 2; ++rt) {
                acc[rt] = __builtin_amdgcn_mfma_f32_16x16x32_f16(Ah[rt][ks], Bh[ks], acc[rt], 0, 0, 0);
                acc[rt] = __builtin_amdgcn_mfma_f32_16x16x32_f16(Al[rt][ks], Bh[ks], acc[rt], 0, 0, 0);
                acc[rt] = __builtin_amdgcn_mfma_f32_16x16x32_f16(Ah[rt][ks], Bl[ks], acc[rt], 0, 0, 0);
            }
        __builtin_amdgcn_s_setprio(0);

        int c = ch * 64 + cm;
        #pragma unroll
        for (int rt = 0; rt < 2; ++rt)
            #pragma unroll
            for (int r = 0; r < 4; ++r) {
                float s = acc[rt][r];
                if (s > best[rt][r]) { best[rt][r] = s; bidx[rt][r] = c; }
            }
        e2cur = e2n;

        __syncthreads();   // next chunk staged + all waves done with bufc
        cur ^= 1;
    }

    // reduce across the 16 code-lanes (m15); min index on ties
    #pragma unroll
    for (int rt = 0; rt < 2; ++rt)
        #pragma unroll
        for (int r = 0; r < 4; ++r) {
            float bv = best[rt][r];
            int   bi = bidx[rt][r];
            #pragma unroll
            for (int m = 1; m <= 8; m <<= 1) {
                float ov = __shfl_xor(bv, m, 64);
                int   oi = __shfl_xor(bi, m, 64);
                if (ov > bv || (ov == bv && oi < bi)) { bv = ov; bi = oi; }
            }
            if (m15 == 0) {
                int rl = rt * 16 + q * 4 + r;
                rv[w][rl] = bv;
                ri[w][rl] = bi;
            }
        }
    __syncthreads();
    if (tid < 128) {
        int rh2 = tid >> 5;      // row-quarter
        int rl  = tid & 31;      // row within quarter
        float bv = rv[rh2 * 4][rl];
        int   bi = ri[rh2 * 4][rl];
        #pragma unroll
        for (int jj = 1; jj < 4; ++jj) {
            float ov = rv[rh2 * 4 + jj][rl];
            int   oi = ri[rh2 * 4 + jj][rl];
            if (ov > bv || (ov == bv && oi < bi)) { bv = ov; bi = oi; }
        }
        ind[n0 + tid] = bi;
        out_ind[n0 + tid] = (float)bi;
        atomicAdd(&bins[bi], 1);
        // commit-loss partial: |x - e_k|^2 = |x|^2 - 2*best_score
        float lp = x2s[tid] - 2.0f * bv;
        #pragma unroll
        for (int off = 32; off > 0; off >>= 1) lp += __shfl_down(lp, off, 64);
        if ((tid & 63) == 0) atomicAdd(loss, lp);
    }
}

// ---------------- scan: shuffle-based, 2 barriers ----------------
__global__ __launch_bounds__(1024) void scan_kernel(const int* __restrict__ bins,
                                                    const float* __restrict__ cluster_size,
                                                    const float* __restrict__ loss,
                                                    int* __restrict__ offsets,
                                                    int* __restrict__ cursor,
                                                    float* __restrict__ out_cs,
                                                    float* __restrict__ ntot,
                                                    float* __restrict__ out_loss) {
    __shared__ int   wtot[16];
    __shared__ float fred[16];
    int t = threadIdx.x;
    int lane = t & 63, wv = t >> 6;
    int b[4];
    float cs[4];
    float csum = 0.f;
    int s = 0;
    #pragma unroll
    for (int e = 0; e < 4; ++e) {
        b[e] = bins[t * 4 + e];
        s += b[e];
        cs[e] = cluster_size[t * 4 + e] * DECAYF + (1.0f - DECAYF) * (float)b[e];
        csum += cs[e];
    }
    int sc = s;
    #pragma unroll
    for (int off = 1; off < 64; off <<= 1) {
        int v = __shfl_up(sc, off, 64);
        if (lane >= off) sc += v;
    }
    float fc = csum;
    #pragma unroll
    for (int off = 32; off > 0; off >>= 1) fc += __shfl_down(fc, off, 64);
    if (lane == 63) wtot[wv] = sc;
    if (lane == 0) fred[wv] = fc;
    __syncthreads();
    if (t < 16) {
        int v = wtot[t];
        int scv = v;
        #pragma unroll
        for (int off = 1; off < 16; off <<= 1) {
            int u = __shfl_up(scv, off, 64);
            if (t >= off) scv += u;
        }
        wtot[t] = scv - v;
    }
    if (t == 0) {
        float tot = 0.f;
        #pragma unroll
        for (int i = 0; i < 16; ++i) tot += fred[i];
        *ntot = tot;
        *out_loss = COMMITW * (*loss) / (float)((size_t)NROWS * DIM);
    }
    __syncthreads();
    int ex = sc - s + wtot[wv];
    #pragma unroll
    for (int e = 0; e < 4; ++e) {
        offsets[t * 4 + e] = ex;
        cursor[t * 4 + e] = ex;
        out_cs[t * 4 + e] = cs[e];
        ex += b[e];
    }
}

// ---------------- reorder rows by code (also emit sorted code list) --------
__global__ __launch_bounds__(256) void reorder_kernel(const int* __restrict__ ind,
                                                      int* __restrict__ cursor,
                                                      int* __restrict__ rowids,
                                                      int* __restrict__ codesorted) {
    int row = blockIdx.x * 256 + threadIdx.x;
    int k = ind[row];
    int pos = atomicAdd(&cursor[k], 1);
    rowids[pos] = row;
    codesorted[pos] = k;
}

// ---------------- segmented esum + out_q: fixed 16-row windows -------------
#define WROWS 16
__global__ __launch_bounds__(256) void segred_kernel(const float* __restrict__ x,
                                                     const float* __restrict__ embed,
                                                     const int* __restrict__ rowids,
                                                     const int* __restrict__ codesorted,
                                                     const int* __restrict__ offsets,
                                                     const int* __restrict__ bins,
                                                     float* __restrict__ esum,
                                                     float* __restrict__ out_q) {
    int tid = threadIdx.x;
    int lane = tid & 63;
    int wv = blockIdx.x * 4 + (tid >> 6);
    int w0 = wv * WROWS;

    int i16 = lane & (WROWS - 1);
    int rowv = rowids[w0 + i16];
    int kv   = codesorted[w0 + i16];

    float2 xv[WROWS];
    #pragma unroll
    for (int i = 0; i < WROWS; ++i) {
        int row = __shfl(rowv, i, 64);
        xv[i] = ((const float2*)(x + (size_t)row * DIM))[lane];
    }

    int curk = __shfl(kv, 0, 64);
    float2 qv = ((const float2*)(embed + (size_t)curk * DIM))[lane];
    float2 acc = {0.f, 0.f};

    #pragma unroll
    for (int i = 0; i < WROWS; ++i) {
        int row = __shfl(rowv, i, 64);
        int k   = __shfl(kv, i, 64);
        if (k != curk) {
            int sbeg = offsets[curk];
            int send = sbeg + bins[curk];
            float* ep = esum + (size_t)curk * DIM + lane * 2;
            if (sbeg >= w0 && send <= w0 + WROWS) {
                *(float2*)ep = acc;
            } else {
                atomicAdd(ep, acc.x);
                atomicAdd(ep + 1, acc.y);
            }
            curk = k;
            acc = (float2){0.f, 0.f};
            qv = ((const float2*)(embed + (size_t)curk * DIM))[lane];
        }
        acc.x += xv[i].x;
        acc.y += xv[i].y;
        ((float2*)(out_q + (size_t)row * DIM))[lane] = qv;
    }
    {
        int sbeg = offsets[curk];
        int send = sbeg + bins[curk];
        float* ep = esum + (size_t)curk * DIM + lane * 2;
        if (sbeg >= w0 && send <= w0 + WROWS) {
            *(float2*)ep = acc;
        } else {
            atomicAdd(ep, acc.x);
            atomicAdd(ep + 1, acc.y);
        }
    }
}

// ---------------- norm: out_norm from esum (streaming) ----------------
__global__ __launch_bounds__(256) void norm_kernel(const float* __restrict__ esum,
                                                   const float* __restrict__ embed_avg,
                                                   const float* __restrict__ out_cs,
                                                   const float* __restrict__ ntot,
                                                   float* __restrict__ out_norm) {
    int idx = blockIdx.x * 256 + threadIdx.x;
    int k = idx >> 6;
    float nt = *ntot;
    float cs = out_cs[k];
    float cluster = (cs + EPSF) / (nt + (float)KCODES * EPSF) * nt;
    float inv = 1.0f / cluster;
    float2 es = ((const float2*)esum)[idx];
    float2 ea = ((const float2*)embed_avg)[idx];
    float2 o;
    o.x = (ea.x * DECAYF + (1.0f - DECAYF) * es.x) * inv;
    o.y = (ea.y * DECAYF + (1.0f - DECAYF) * es.y) * inv;
    ((float2*)out_norm)[idx] = o;
}

extern "C" void kernel_launch(void* const* d_in, const int* in_sizes, int n_in,
                              void* d_out, int out_size, void* d_ws, size_t ws_size,
                              hipStream_t stream) {
    const float* x            = (const float*)d_in[0];
    const float* embed        = (const float*)d_in[1];
    const float* cluster_size = (const float*)d_in[2];
    const float* embed_avg    = (const float*)d_in[3];

    float* out      = (float*)d_out;
    float* out_q    = out;                               // 4194304
    float* out_ind  = out + 4194304;                     // 32768
    float* out_loss = out_ind + 32768;                   // 1
    float* out_cs   = out_loss + 1;                      // 4096
    float* out_norm = out_cs + 4096;                     // 524288

    // workspace layout (bytes)
    char* ws = (char*)d_ws;
    _Float16* estg = (_Float16*)ws;                      // 2,097,152
    float* e2h   = (float*)(ws + 2097152);               // 16,384
    int*   ind   = (int*)(ws + 2113536);                 // 131,072
    int*   offsets = (int*)(ws + 2244608);               // 16,384
    int*   cursor  = (int*)(ws + 2260992);               // 16,384
    int*   rowids  = (int*)(ws + 2277376);               // 131,072
    int*   codesorted = (int*)(ws + 2408448);            // 131,072
    float* loss  = (float*)(ws + 2539520);               // 4 (pad to 256)
    float* ntot  = loss + 1;
    int*   bins  = (int*)(ws + 2539776);                 // 16,384
    float* esum  = (float*)(ws + 2556160);               // 2,097,152

    // zero loss/pad + bins + esum (contiguous)
    hipMemsetAsync(ws + 2539520, 0, 256 + 16384 + 2097152, stream);

    esplit_kernel<<<KCODES / 4, 256, 0, stream>>>(embed, estg, e2h);
    argmax_kernel<<<NROWS / 128, 1024, 0, stream>>>(x, estg, e2h, ind, out_ind,
                                                    bins, loss);
    scan_kernel<<<1, 1024, 0, stream>>>(bins, cluster_size, loss, offsets, cursor,
                                        out_cs, ntot, out_loss);
    reorder_kernel<<<NROWS / 256, 256, 0, stream>>>(ind, cursor, rowids, codesorted);
    segred_kernel<<<NROWS / WROWS / 4, 256, 0, stream>>>(x, embed, rowids, codesorted,
                                                         offsets, bins, esum, out_q);
    norm_kernel<<<KCODES * DIM / 2 / 256, 256, 0, stream>>>(esum, embed_avg, out_cs,
                                                            ntot, out_norm);
}

// Round 3
// 227.093 us; speedup vs baseline: 1.1556x; 1.1556x over previous
//
#include <hip/hip_runtime.h>

#define NROWS 32768
#define DIM   128
#define KCODES 4096
#define DECAYF 0.8f
#define EPSF 1e-5f
#define COMMITW 0.25f

// R3 chunking: 128 chunks x 32 codes. Per-chunk blob = 16KB B-frags + 1KB e2/pad.
#define CH_N 128
#define CH_BYTES 17408
#define ESTG_BYTES (CH_N * CH_BYTES)   // 2,228,224

typedef _Float16 half8 __attribute__((ext_vector_type(8)));
typedef _Float16 half2v __attribute__((ext_vector_type(2)));
typedef float float4v __attribute__((ext_vector_type(4)));

// direct global->LDS: lane i's 16B from gsrc(per-lane addr) lands at ldsdst + i*16
__device__ inline void stage1k(const char* gsrc, char* ldsdst) {
    __builtin_amdgcn_global_load_lds(
        (const __attribute__((address_space(1))) void*)gsrc,
        (__attribute__((address_space(3))) void*)ldsdst, 16, 0, 0);
}

// ---------------- embed -> staged chunk blobs ----------------
// Blob layout per chunk (17408 B):
//   B-part 16KB: frag f = (pl*4+ks)*2 + j  (16 frags x 1KB), within frag:
//     byte = (q*16 + m15)*16 + e*2   (exactly one wave's ds_read_b128 slab)
//   e2-part @16384: 32 x f32 (-indexed by cm = code&31), rest pad.
__global__ __launch_bounds__(256) void esplit_kernel(const float* __restrict__ embed,
                                                     char* __restrict__ estg) {
    int code = blockIdx.x * 4 + (threadIdx.x >> 6);
    int lane = threadIdx.x & 63;
    float2 v = ((const float2*)(embed + (size_t)code * DIM))[lane];
    float s = v.x * v.x + v.y * v.y;
    #pragma unroll
    for (int off = 32; off > 0; off >>= 1) s += __shfl_down(s, off, 64);

    int ch = code >> 5;
    int jj = (code >> 4) & 1;
    int m15c = code & 15;
    char* cbase = estg + (size_t)ch * CH_BYTES;

    if (lane == 0) *(float*)(cbase + 16384 + (code & 31) * 4) = 0.5f * s;

    int d = lane * 2;
    int ks = d >> 5, q = (d >> 3) & 3, e = d & 7;
    _Float16 h0 = (_Float16)v.x, l0 = (_Float16)(v.x - (float)h0);
    _Float16 h1 = (_Float16)v.y, l1 = (_Float16)(v.y - (float)h1);
    size_t fh = (size_t)((0 * 4 + ks) * 2 + jj) * 1024 + (size_t)(q * 16 + m15c) * 16 + e * 2;
    size_t fl = (size_t)((1 * 4 + ks) * 2 + jj) * 1024 + (size_t)(q * 16 + m15c) * 16 + e * 2;
    *(half2v*)(cbase + fh) = (half2v){h0, h1};
    *(half2v*)(cbase + fl) = (half2v){l0, l1};
}

// ---------------- MFMA argmax: 128 rows/block, 16 waves, ring pipeline ----
// R3: T3+T4 port. 4-deep 17KB LDS ring, counted s_waitcnt vmcnt(2) (3 chunks
// in flight, never drain to 0), ONE raw s_barrier per chunk, stage for ch+3
// issued right after the barrier. e2 rides the staged blob -> the K-loop's
// only vmcnt traffic is the ring stages (counting stays exact).
// Waves: j = w&1 (16-code half), rh = w>>1 (16-row tile). 4 waves/SIMD.
__global__ __launch_bounds__(1024, 4) void argmax_kernel(const float* __restrict__ x,
                                                         const char* __restrict__ estg,
                                                         int* __restrict__ ind,
                                                         float* __restrict__ out_ind,
                                                         int* __restrict__ bins,
                                                         float* __restrict__ loss) {
    __shared__ __align__(16) char ring[4][CH_BYTES];
    __shared__ float rv[16][16];
    __shared__ int   ri[16][16];
    __shared__ float x2s[128];

    int tid = threadIdx.x;
    int lane = tid & 63;
    int w = tid >> 6;          // 0..15
    int j = w & 1;             // 16-code half of the 32-code chunk
    int rh = w >> 1;           // 16-row tile 0..7
    int m15 = lane & 15;
    int q = (lane >> 4) & 3;
    int n0 = blockIdx.x * 128;

    // prologue: stage chunks 0..2 into ring slots 0..2 (wave w owns blob KB w;
    // wave 0 additionally stages the e2 KB)
    #pragma unroll
    for (int p = 0; p < 3; ++p) {
        const char* g = estg + (size_t)p * CH_BYTES + (size_t)w * 1024 + (size_t)lane * 16;
        stage1k(g, &ring[p][w * 1024]);
        if (w == 0) stage1k(g + 16384, &ring[p][16384]);
    }

    // A frags: rows n0 + rh*16 + m15 (each row handled by the j=0 and j=1 wave pair)
    half8 Ah[4], Al[4];
    float xsq = 0.f;
    #pragma unroll
    for (int ks = 0; ks < 4; ++ks) {
        const float* p = x + (size_t)(n0 + rh * 16 + m15) * DIM + ks * 32 + q * 8;
        float4 a = *(const float4*)p;
        float4 b = *(const float4*)(p + 4);
        float f[8] = {a.x, a.y, a.z, a.w, b.x, b.y, b.z, b.w};
        half8 H, L;
        #pragma unroll
        for (int e = 0; e < 8; ++e) {
            _Float16 h = (_Float16)f[e];
            H[e] = h;
            L[e] = (_Float16)(f[e] - (float)h);
            xsq += f[e] * f[e];
        }
        Ah[ks] = H;
        Al[ks] = L;
    }
    xsq += __shfl_xor(xsq, 16, 64);
    xsq += __shfl_xor(xsq, 32, 64);
    if (j == 0 && lane < 16) x2s[rh * 16 + m15] = xsq;

    float best[4];
    int   bidx[4];
    #pragma unroll
    for (int r = 0; r < 4; ++r) { best[r] = -3.0e38f; bidx[r] = 0; }

    const int cm = j * 16 + m15;

    #pragma unroll 1
    for (int ch = 0; ch < CH_N; ++ch) {
        // oldest in-flight stage (chunk ch) must have landed; keep 2 in flight.
        asm volatile("s_waitcnt vmcnt(2)" ::: "memory");
        __builtin_amdgcn_s_barrier();
        asm volatile("" ::: "memory");

        // issue stage for ch+3 into the slot last read at ch-1 (all waves are
        // provably past it: they crossed this chunk's barrier)
        if (ch + 3 < CH_N) {
            const char* g = estg + (size_t)(ch + 3) * CH_BYTES + (size_t)w * 1024 + (size_t)lane * 16;
            char* d = &ring[(ch + 3) & 3][w * 1024];
            stage1k(g, d);
            if (w == 0) stage1k(g + 16384, &ring[(ch + 3) & 3][16384]);
        }

        const char* buf = ring[ch & 3];
        float e2 = *(const float*)(buf + 16384 + cm * 4);

        float4v acc = (float4v){-e2, -e2, -e2, -e2};
        #pragma unroll
        for (int ks = 0; ks < 4; ++ks) {
            half8 Bh = *(const half8*)(buf + (size_t)((0 * 4 + ks) * 2 + j) * 1024 + (size_t)lane * 16);
            half8 Bl = *(const half8*)(buf + (size_t)((1 * 4 + ks) * 2 + j) * 1024 + (size_t)lane * 16);
            acc = __builtin_amdgcn_mfma_f32_16x16x32_f16(Ah[ks], Bh, acc, 0, 0, 0);
            acc = __builtin_amdgcn_mfma_f32_16x16x32_f16(Al[ks], Bh, acc, 0, 0, 0);
            acc = __builtin_amdgcn_mfma_f32_16x16x32_f16(Ah[ks], Bl, acc, 0, 0, 0);
        }

        int c = ch * 32 + cm;
        #pragma unroll
        for (int r = 0; r < 4; ++r) {
            float s = acc[r];
            if (s > best[r]) { best[r] = s; bidx[r] = c; }
        }
    }

    // reduce across the 16 code-lanes (m15); min index on ties
    #pragma unroll
    for (int r = 0; r < 4; ++r) {
        float bv = best[r];
        int   bi = bidx[r];
        #pragma unroll
        for (int m = 1; m <= 8; m <<= 1) {
            float ov = __shfl_xor(bv, m, 64);
            int   oi = __shfl_xor(bi, m, 64);
            if (ov > bv || (ov == bv && oi < bi)) { bv = ov; bi = oi; }
        }
        if (m15 == 0) {
            rv[w][q * 4 + r] = bv;
            ri[w][q * 4 + r] = bi;
        }
    }
    __syncthreads();
    if (tid < 128) {
        int rh2 = tid >> 4;      // row-tile
        int rr  = tid & 15;      // row within tile
        float bv = rv[rh2 * 2][rr];
        int   bi = ri[rh2 * 2][rr];
        float ov = rv[rh2 * 2 + 1][rr];
        int   oi = ri[rh2 * 2 + 1][rr];
        if (ov > bv || (ov == bv && oi < bi)) { bv = ov; bi = oi; }
        ind[n0 + tid] = bi;
        out_ind[n0 + tid] = (float)bi;
        atomicAdd(&bins[bi], 1);
        // commit-loss partial: |x - e_k|^2 = |x|^2 - 2*best_score
        float lp = x2s[tid] - 2.0f * bv;
        #pragma unroll
        for (int off = 32; off > 0; off >>= 1) lp += __shfl_down(lp, off, 64);
        if ((tid & 63) == 0) atomicAdd(loss, lp);
    }
}

// ---------------- scan: shuffle-based, 2 barriers ----------------
__global__ __launch_bounds__(1024) void scan_kernel(const int* __restrict__ bins,
                                                    const float* __restrict__ cluster_size,
                                                    const float* __restrict__ loss,
                                                    int* __restrict__ offsets,
                                                    int* __restrict__ cursor,
                                                    float* __restrict__ out_cs,
                                                    float* __restrict__ ntot,
                                                    float* __restrict__ out_loss) {
    __shared__ int   wtot[16];
    __shared__ float fred[16];
    int t = threadIdx.x;
    int lane = t & 63, wv = t >> 6;
    int b[4];
    float cs[4];
    float csum = 0.f;
    int s = 0;
    #pragma unroll
    for (int e = 0; e < 4; ++e) {
        b[e] = bins[t * 4 + e];
        s += b[e];
        cs[e] = cluster_size[t * 4 + e] * DECAYF + (1.0f - DECAYF) * (float)b[e];
        csum += cs[e];
    }
    int sc = s;
    #pragma unroll
    for (int off = 1; off < 64; off <<= 1) {
        int v = __shfl_up(sc, off, 64);
        if (lane >= off) sc += v;
    }
    float fc = csum;
    #pragma unroll
    for (int off = 32; off > 0; off >>= 1) fc += __shfl_down(fc, off, 64);
    if (lane == 63) wtot[wv] = sc;
    if (lane == 0) fred[wv] = fc;
    __syncthreads();
    if (t < 16) {
        int v = wtot[t];
        int scv = v;
        #pragma unroll
        for (int off = 1; off < 16; off <<= 1) {
            int u = __shfl_up(scv, off, 64);
            if (t >= off) scv += u;
        }
        wtot[t] = scv - v;
    }
    if (t == 0) {
        float tot = 0.f;
        #pragma unroll
        for (int i = 0; i < 16; ++i) tot += fred[i];
        *ntot = tot;
        *out_loss = COMMITW * (*loss) / (float)((size_t)NROWS * DIM);
    }
    __syncthreads();
    int ex = sc - s + wtot[wv];
    #pragma unroll
    for (int e = 0; e < 4; ++e) {
        offsets[t * 4 + e] = ex;
        cursor[t * 4 + e] = ex;
        out_cs[t * 4 + e] = cs[e];
        ex += b[e];
    }
}

// ---------------- reorder rows by code (also emit sorted code list) --------
__global__ __launch_bounds__(256) void reorder_kernel(const int* __restrict__ ind,
                                                      int* __restrict__ cursor,
                                                      int* __restrict__ rowids,
                                                      int* __restrict__ codesorted) {
    int row = blockIdx.x * 256 + threadIdx.x;
    int k = ind[row];
    int pos = atomicAdd(&cursor[k], 1);
    rowids[pos] = row;
    codesorted[pos] = k;
}

// ---------------- segmented esum + out_q: fixed 16-row windows -------------
#define WROWS 16
__global__ __launch_bounds__(256) void segred_kernel(const float* __restrict__ x,
                                                     const float* __restrict__ embed,
                                                     const int* __restrict__ rowids,
                                                     const int* __restrict__ codesorted,
                                                     const int* __restrict__ offsets,
                                                     const int* __restrict__ bins,
                                                     float* __restrict__ esum,
                                                     float* __restrict__ out_q) {
    int tid = threadIdx.x;
    int lane = tid & 63;
    int wv = blockIdx.x * 4 + (tid >> 6);
    int w0 = wv * WROWS;

    int i16 = lane & (WROWS - 1);
    int rowv = rowids[w0 + i16];
    int kv   = codesorted[w0 + i16];

    float2 xv[WROWS];
    #pragma unroll
    for (int i = 0; i < WROWS; ++i) {
        int row = __shfl(rowv, i, 64);
        xv[i] = ((const float2*)(x + (size_t)row * DIM))[lane];
    }

    int curk = __shfl(kv, 0, 64);
    float2 qv = ((const float2*)(embed + (size_t)curk * DIM))[lane];
    float2 acc = {0.f, 0.f};

    #pragma unroll
    for (int i = 0; i < WROWS; ++i) {
        int row = __shfl(rowv, i, 64);
        int k   = __shfl(kv, i, 64);
        if (k != curk) {
            int sbeg = offsets[curk];
            int send = sbeg + bins[curk];
            float* ep = esum + (size_t)curk * DIM + lane * 2;
            if (sbeg >= w0 && send <= w0 + WROWS) {
                *(float2*)ep = acc;
            } else {
                atomicAdd(ep, acc.x);
                atomicAdd(ep + 1, acc.y);
            }
            curk = k;
            acc = (float2){0.f, 0.f};
            qv = ((const float2*)(embed + (size_t)curk * DIM))[lane];
        }
        acc.x += xv[i].x;
        acc.y += xv[i].y;
        ((float2*)(out_q + (size_t)row * DIM))[lane] = qv;
    }
    {
        int sbeg = offsets[curk];
        int send = sbeg + bins[curk];
        float* ep = esum + (size_t)curk * DIM + lane * 2;
        if (sbeg >= w0 && send <= w0 + WROWS) {
            *(float2*)ep = acc;
        } else {
            atomicAdd(ep, acc.x);
            atomicAdd(ep + 1, acc.y);
        }
    }
}

// ---------------- norm: out_norm from esum (streaming) ----------------
__global__ __launch_bounds__(256) void norm_kernel(const float* __restrict__ esum,
                                                   const float* __restrict__ embed_avg,
                                                   const float* __restrict__ out_cs,
                                                   const float* __restrict__ ntot,
                                                   float* __restrict__ out_norm) {
    int idx = blockIdx.x * 256 + threadIdx.x;
    int k = idx >> 6;
    float nt = *ntot;
    float cs = out_cs[k];
    float cluster = (cs + EPSF) / (nt + (float)KCODES * EPSF) * nt;
    float inv = 1.0f / cluster;
    float2 es = ((const float2*)esum)[idx];
    float2 ea = ((const float2*)embed_avg)[idx];
    float2 o;
    o.x = (ea.x * DECAYF + (1.0f - DECAYF) * es.x) * inv;
    o.y = (ea.y * DECAYF + (1.0f - DECAYF) * es.y) * inv;
    ((float2*)out_norm)[idx] = o;
}

extern "C" void kernel_launch(void* const* d_in, const int* in_sizes, int n_in,
                              void* d_out, int out_size, void* d_ws, size_t ws_size,
                              hipStream_t stream) {
    const float* x            = (const float*)d_in[0];
    const float* embed        = (const float*)d_in[1];
    const float* cluster_size = (const float*)d_in[2];
    const float* embed_avg    = (const float*)d_in[3];

    float* out      = (float*)d_out;
    float* out_q    = out;                               // 4194304
    float* out_ind  = out + 4194304;                     // 32768
    float* out_loss = out_ind + 32768;                   // 1
    float* out_cs   = out_loss + 1;                      // 4096
    float* out_norm = out_cs + 4096;                     // 524288

    // workspace layout (bytes). estg and esum ALIAS (estg dead after argmax;
    // esum zeroed after reorder launch, used by segred/norm).
    char* ws = (char*)d_ws;
    char*  estg = ws;                                    // 2,228,224
    float* esum = (float*)ws;                            // 2,097,152 (aliased)
    int*   ind  = (int*)(ws + 2228224);                  // 131,072
    int*   offsets = (int*)(ws + 2359296);               // 16,384
    int*   cursor  = (int*)(ws + 2375680);               // 16,384
    int*   rowids  = (int*)(ws + 2392064);               // 131,072
    int*   codesorted = (int*)(ws + 2523136);            // 131,072
    float* loss = (float*)(ws + 2654208);                // 4 (pad to 256)
    float* ntot = loss + 1;
    int*   bins = (int*)(ws + 2654464);                  // 16,384

    // zero loss/pad + bins (contiguous) before argmax
    hipMemsetAsync(ws + 2654208, 0, 256 + 16384, stream);

    esplit_kernel<<<KCODES / 4, 256, 0, stream>>>(embed, estg);
    argmax_kernel<<<NROWS / 128, 1024, 0, stream>>>(x, estg, ind, out_ind,
                                                    bins, loss);
    scan_kernel<<<1, 1024, 0, stream>>>(bins, cluster_size, loss, offsets, cursor,
                                        out_cs, ntot, out_loss);
    reorder_kernel<<<NROWS / 256, 256, 0, stream>>>(ind, cursor, rowids, codesorted);
    // estg region is dead now; zero it for use as esum (stream-ordered)
    hipMemsetAsync(ws, 0, 2097152, stream);
    segred_kernel<<<NROWS / WROWS / 4, 256, 0, stream>>>(x, embed, rowids, codesorted,
                                                         offsets, bins, esum, out_q);
    norm_kernel<<<KCODES * DIM / 2 / 256, 256, 0, stream>>>(esum, embed_avg, out_cs,
                                                            ntot, out_norm);
}

// Round 4
// 223.785 us; speedup vs baseline: 1.1727x; 1.0148x over previous
//
#include <hip/hip_runtime.h>

#define NROWS 32768
#define DIM   128
#define KCODES 4096
#define DECAYF 0.8f
#define EPSF 1e-5f
#define COMMITW 0.25f

// R4 chunking: 64 chunks x 64 codes. Blob = 32KB B-frags + 256B e2.
#define CH_N 64
#define CH_BYTES 33024
#define ESTG_BYTES (CH_N * CH_BYTES)   // 2,113,536

typedef _Float16 half8 __attribute__((ext_vector_type(8)));
typedef _Float16 half2v __attribute__((ext_vector_type(2)));
typedef float float4v __attribute__((ext_vector_type(4)));

// direct global->LDS: lane i's 16B (or 4B) lands at ldsdst + i*width
__device__ inline void stage1k(const char* gsrc, char* ldsdst) {
    __builtin_amdgcn_global_load_lds(
        (const __attribute__((address_space(1))) void*)gsrc,
        (__attribute__((address_space(3))) void*)ldsdst, 16, 0, 0);
}
__device__ inline void stage256(const char* gsrc, char* ldsdst) {
    __builtin_amdgcn_global_load_lds(
        (const __attribute__((address_space(1))) void*)gsrc,
        (__attribute__((address_space(3))) void*)ldsdst, 4, 0, 0);
}

// ---------------- embed -> staged chunk blobs ----------------
// Blob (33024 B): B-part 32KB, frag f = (pl*4+ks)*4 + j  (32 frags x 1KB);
//   within frag: byte = (q*16 + m15)*16 + e*2  (one wave's contiguous
//   ds_read_b128 slab). e2-part @32768: 64 x f32 indexed by c6.
__global__ __launch_bounds__(256) void esplit_kernel(const float* __restrict__ embed,
                                                     char* __restrict__ estg) {
    int code = blockIdx.x * 4 + (threadIdx.x >> 6);
    int lane = threadIdx.x & 63;
    float2 v = ((const float2*)(embed + (size_t)code * DIM))[lane];
    float s = v.x * v.x + v.y * v.y;
    #pragma unroll
    for (int off = 32; off > 0; off >>= 1) s += __shfl_down(s, off, 64);

    int ch = code >> 6, c6 = code & 63;
    int jj = c6 >> 4, m15c = c6 & 15;
    char* cbase = estg + (size_t)ch * CH_BYTES;
    if (lane == 0) *(float*)(cbase + 32768 + c6 * 4) = 0.5f * s;

    int d = lane * 2;
    int ks = d >> 5, q = (d >> 3) & 3, e = d & 7;
    _Float16 h0 = (_Float16)v.x, l0 = (_Float16)(v.x - (float)h0);
    _Float16 h1 = (_Float16)v.y, l1 = (_Float16)(v.y - (float)h1);
    size_t fh = (size_t)((0 * 4 + ks) * 4 + jj) * 1024 + (size_t)(q * 16 + m15c) * 16 + e * 2;
    size_t fl = (size_t)((1 * 4 + ks) * 4 + jj) * 1024 + (size_t)(q * 16 + m15c) * 16 + e * 2;
    *(half2v*)(cbase + fh) = (half2v){h0, h1};
    *(half2v*)(cbase + fl) = (half2v){l0, l1};
}

// ---------------- MFMA argmax: 128 rows/block, 8 waves, LDS ring ----------
// R4 = R0 tiling (64 rows/wave -> B-read amplification 2x, not R3's 8x)
//    + R3 delivery (3-deep LDS ring, counted vmcnt, raw s_barrier, 1/chunk).
// Per chunk per CU: MFMA 1862 cy vs LDS-read 512 cy vs L2-stage 590 cy.
// Uniform 5 stage-loads/wave/chunk (e2 staged redundantly by all waves) so
// the vmcnt count is exact; final chunk drains with vmcnt(0).
__global__ __launch_bounds__(512, 2) void argmax_kernel(const float* __restrict__ x,
                                                        const char* __restrict__ estg,
                                                        int* __restrict__ ind,
                                                        float* __restrict__ out_ind,
                                                        int* __restrict__ bins,
                                                        float* __restrict__ loss) {
    __shared__ __align__(16) char ring[3][CH_BYTES];
    __shared__ float rv[8][64];
    __shared__ int   ri[8][64];
    __shared__ float x2s[128];

    int tid = threadIdx.x;
    int lane = tid & 63;
    int w = tid >> 6;          // 0..7
    int j = w & 3;             // 16-code quarter of the 64-code chunk
    int rh = w >> 2;           // 64-row half
    int m15 = lane & 15;
    int q = (lane >> 4) & 3;
    int n0 = blockIdx.x * 128;

    // A frags FIRST (so the vmcnt FIFO is A..., stage0, stage1 -> vmcnt(5)
    // at iter 0 leaves exactly stage1 outstanding)
    half8 Ah[4][4], Al[4][4];
    float xsq[4];
    #pragma unroll
    for (int rt = 0; rt < 4; ++rt) {
        xsq[rt] = 0.f;
        #pragma unroll
        for (int ks = 0; ks < 4; ++ks) {
            const float* p = x + (size_t)(n0 + rh * 64 + rt * 16 + m15) * DIM + ks * 32 + q * 8;
            float4 a = *(const float4*)p;
            float4 b = *(const float4*)(p + 4);
            float f[8] = {a.x, a.y, a.z, a.w, b.x, b.y, b.z, b.w};
            half8 H, L;
            #pragma unroll
            for (int e = 0; e < 8; ++e) {
                _Float16 h = (_Float16)f[e];
                H[e] = h;
                L[e] = (_Float16)(f[e] - (float)h);
                xsq[rt] += f[e] * f[e];
            }
            Ah[rt][ks] = H;
            Al[rt][ks] = L;
        }
        xsq[rt] += __shfl_xor(xsq[rt], 16, 64);
        xsq[rt] += __shfl_xor(xsq[rt], 32, 64);
    }
    if (j == 0 && lane < 16) {
        #pragma unroll
        for (int rt = 0; rt < 4; ++rt) x2s[rh * 64 + rt * 16 + m15] = xsq[rt];
    }

    // prologue: stage chunks 0,1 into ring slots 0,1 (wave owns 4KB + e2)
    #pragma unroll
    for (int p = 0; p < 2; ++p) {
        const char* g = estg + (size_t)p * CH_BYTES + (size_t)w * 4096 + (size_t)lane * 16;
        char* d = &ring[p][w * 4096];
        #pragma unroll
        for (int i = 0; i < 4; ++i) stage1k(g + i * 1024, d + i * 1024);
        stage256(estg + (size_t)p * CH_BYTES + 32768 + (size_t)lane * 4, &ring[p][32768]);
    }

    float best[4][4];
    int   bidx[4][4];
    #pragma unroll
    for (int rt = 0; rt < 4; ++rt)
        #pragma unroll
        for (int r = 0; r < 4; ++r) { best[rt][r] = -3.0e38f; bidx[rt][r] = 0; }

    const int cm = j * 16 + m15;

    #pragma unroll 1
    for (int ch = 0; ch < CH_N; ++ch) {
        // own stage(ch) loads landed (5/iter in flight for stage(ch+1));
        // barrier makes it collective: EVERYONE's stage(ch) landed and
        // everyone is done reading buf[(ch-1)%3].
        if (ch + 1 == CH_N) asm volatile("s_waitcnt vmcnt(0)" ::: "memory");
        else                asm volatile("s_waitcnt vmcnt(5)" ::: "memory");
        __builtin_amdgcn_s_barrier();
        asm volatile("" ::: "memory");

        // stage ch+2 into buf[(ch+2)%3] == buf[(ch-1)%3] (provably free)
        if (ch + 2 < CH_N) {
            const char* g = estg + (size_t)(ch + 2) * CH_BYTES + (size_t)w * 4096 + (size_t)lane * 16;
            char* d = &ring[(ch + 2) % 3][w * 4096];
            #pragma unroll
            for (int i = 0; i < 4; ++i) stage1k(g + i * 1024, d + i * 1024);
            stage256(estg + (size_t)(ch + 2) * CH_BYTES + 32768 + (size_t)lane * 4,
                     &ring[(ch + 2) % 3][32768]);
        }

        const char* buf = ring[ch % 3];
        float e2 = *(const float*)(buf + 32768 + cm * 4);

        float4v acc[4];
        #pragma unroll
        for (int rt = 0; rt < 4; ++rt) acc[rt] = (float4v){-e2, -e2, -e2, -e2};

        #pragma unroll
        for (int ks = 0; ks < 4; ++ks) {
            half8 Bh = *(const half8*)(buf + (size_t)((0 * 4 + ks) * 4 + j) * 1024 + (size_t)lane * 16);
            half8 Bl = *(const half8*)(buf + (size_t)((1 * 4 + ks) * 4 + j) * 1024 + (size_t)lane * 16);
            #pragma unroll
            for (int rt = 0; rt < 4; ++rt) {
                acc[rt] = __builtin_amdgcn_mfma_f32_16x16x32_f16(Ah[rt][ks], Bh, acc[rt], 0, 0, 0);
                acc[rt] = __builtin_amdgcn_mfma_f32_16x16x32_f16(Al[rt][ks], Bh, acc[rt], 0, 0, 0);
                acc[rt] = __builtin_amdgcn_mfma_f32_16x16x32_f16(Ah[rt][ks], Bl, acc[rt], 0, 0, 0);
            }
        }

        int c = ch * 64 + cm;
        #pragma unroll
        for (int rt = 0; rt < 4; ++rt)
            #pragma unroll
            for (int r = 0; r < 4; ++r) {
                float s = acc[rt][r];
                if (s > best[rt][r]) { best[rt][r] = s; bidx[rt][r] = c; }
            }
    }

    // reduce across the 16 code-lanes (m15); min index on ties
    #pragma unroll
    for (int rt = 0; rt < 4; ++rt)
        #pragma unroll
        for (int r = 0; r < 4; ++r) {
            float bv = best[rt][r];
            int   bi = bidx[rt][r];
            #pragma unroll
            for (int m = 1; m <= 8; m <<= 1) {
                float ov = __shfl_xor(bv, m, 64);
                int   oi = __shfl_xor(bi, m, 64);
                if (ov > bv || (ov == bv && oi < bi)) { bv = ov; bi = oi; }
            }
            if (m15 == 0) {
                int rl = rt * 16 + q * 4 + r;
                rv[w][rl] = bv;
                ri[w][rl] = bi;
            }
        }
    __syncthreads();
    if (tid < 128) {
        int rhh = tid >> 6;
        int rl  = tid & 63;
        float bv = rv[rhh * 4][rl];
        int   bi = ri[rhh * 4][rl];
        #pragma unroll
        for (int jj = 1; jj < 4; ++jj) {
            float ov = rv[rhh * 4 + jj][rl];
            int   oi = ri[rhh * 4 + jj][rl];
            if (ov > bv || (ov == bv && oi < bi)) { bv = ov; bi = oi; }
        }
        ind[n0 + tid] = bi;
        out_ind[n0 + tid] = (float)bi;
        atomicAdd(&bins[bi], 1);
        // commit-loss partial: |x - e_k|^2 = |x|^2 - 2*best_score
        float lp = x2s[tid] - 2.0f * bv;
        #pragma unroll
        for (int off = 32; off > 0; off >>= 1) lp += __shfl_down(lp, off, 64);
        if ((tid & 63) == 0) atomicAdd(loss, lp);
    }
}

// ---------------- scan: shuffle-based, 2 barriers ----------------
__global__ __launch_bounds__(1024) void scan_kernel(const int* __restrict__ bins,
                                                    const float* __restrict__ cluster_size,
                                                    const float* __restrict__ loss,
                                                    int* __restrict__ offsets,
                                                    int* __restrict__ cursor,
                                                    float* __restrict__ out_cs,
                                                    float* __restrict__ ntot,
                                                    float* __restrict__ out_loss) {
    __shared__ int   wtot[16];
    __shared__ float fred[16];
    int t = threadIdx.x;
    int lane = t & 63, wv = t >> 6;
    int b[4];
    float cs[4];
    float csum = 0.f;
    int s = 0;
    #pragma unroll
    for (int e = 0; e < 4; ++e) {
        b[e] = bins[t * 4 + e];
        s += b[e];
        cs[e] = cluster_size[t * 4 + e] * DECAYF + (1.0f - DECAYF) * (float)b[e];
        csum += cs[e];
    }
    int sc = s;
    #pragma unroll
    for (int off = 1; off < 64; off <<= 1) {
        int v = __shfl_up(sc, off, 64);
        if (lane >= off) sc += v;
    }
    float fc = csum;
    #pragma unroll
    for (int off = 32; off > 0; off >>= 1) fc += __shfl_down(fc, off, 64);
    if (lane == 63) wtot[wv] = sc;
    if (lane == 0) fred[wv] = fc;
    __syncthreads();
    if (t < 16) {
        int v = wtot[t];
        int scv = v;
        #pragma unroll
        for (int off = 1; off < 16; off <<= 1) {
            int u = __shfl_up(scv, off, 64);
            if (t >= off) scv += u;
        }
        wtot[t] = scv - v;
    }
    if (t == 0) {
        float tot = 0.f;
        #pragma unroll
        for (int i = 0; i < 16; ++i) tot += fred[i];
        *ntot = tot;
        *out_loss = COMMITW * (*loss) / (float)((size_t)NROWS * DIM);
    }
    __syncthreads();
    int ex = sc - s + wtot[wv];
    #pragma unroll
    for (int e = 0; e < 4; ++e) {
        offsets[t * 4 + e] = ex;
        cursor[t * 4 + e] = ex;
        out_cs[t * 4 + e] = cs[e];
        ex += b[e];
    }
}

// ---------------- reorder rows by code (also emit sorted code list) --------
__global__ __launch_bounds__(256) void reorder_kernel(const int* __restrict__ ind,
                                                      int* __restrict__ cursor,
                                                      int* __restrict__ rowids,
                                                      int* __restrict__ codesorted) {
    int row = blockIdx.x * 256 + threadIdx.x;
    int k = ind[row];
    int pos = atomicAdd(&cursor[k], 1);
    rowids[pos] = row;
    codesorted[pos] = k;
}

// ---------------- segmented esum + out_q: fixed 16-row windows -------------
#define WROWS 16
__global__ __launch_bounds__(256) void segred_kernel(const float* __restrict__ x,
                                                     const float* __restrict__ embed,
                                                     const int* __restrict__ rowids,
                                                     const int* __restrict__ codesorted,
                                                     const int* __restrict__ offsets,
                                                     const int* __restrict__ bins,
                                                     float* __restrict__ esum,
                                                     float* __restrict__ out_q) {
    int tid = threadIdx.x;
    int lane = tid & 63;
    int wv = blockIdx.x * 4 + (tid >> 6);
    int w0 = wv * WROWS;

    int i16 = lane & (WROWS - 1);
    int rowv = rowids[w0 + i16];
    int kv   = codesorted[w0 + i16];

    float2 xv[WROWS];
    #pragma unroll
    for (int i = 0; i < WROWS; ++i) {
        int row = __shfl(rowv, i, 64);
        xv[i] = ((const float2*)(x + (size_t)row * DIM))[lane];
    }

    int curk = __shfl(kv, 0, 64);
    float2 qv = ((const float2*)(embed + (size_t)curk * DIM))[lane];
    float2 acc = {0.f, 0.f};

    #pragma unroll
    for (int i = 0; i < WROWS; ++i) {
        int row = __shfl(rowv, i, 64);
        int k   = __shfl(kv, i, 64);
        if (k != curk) {
            int sbeg = offsets[curk];
            int send = sbeg + bins[curk];
            float* ep = esum + (size_t)curk * DIM + lane * 2;
            if (sbeg >= w0 && send <= w0 + WROWS) {
                *(float2*)ep = acc;
            } else {
                atomicAdd(ep, acc.x);
                atomicAdd(ep + 1, acc.y);
            }
            curk = k;
            acc = (float2){0.f, 0.f};
            qv = ((const float2*)(embed + (size_t)curk * DIM))[lane];
        }
        acc.x += xv[i].x;
        acc.y += xv[i].y;
        ((float2*)(out_q + (size_t)row * DIM))[lane] = qv;
    }
    {
        int sbeg = offsets[curk];
        int send = sbeg + bins[curk];
        float* ep = esum + (size_t)curk * DIM + lane * 2;
        if (sbeg >= w0 && send <= w0 + WROWS) {
            *(float2*)ep = acc;
        } else {
            atomicAdd(ep, acc.x);
            atomicAdd(ep + 1, acc.y);
        }
    }
}

// ---------------- norm: out_norm from esum (streaming) ----------------
__global__ __launch_bounds__(256) void norm_kernel(const float* __restrict__ esum,
                                                   const float* __restrict__ embed_avg,
                                                   const float* __restrict__ out_cs,
                                                   const float* __restrict__ ntot,
                                                   float* __restrict__ out_norm) {
    int idx = blockIdx.x * 256 + threadIdx.x;
    int k = idx >> 6;
    float nt = *ntot;
    float cs = out_cs[k];
    float cluster = (cs + EPSF) / (nt + (float)KCODES * EPSF) * nt;
    float inv = 1.0f / cluster;
    float2 es = ((const float2*)esum)[idx];
    float2 ea = ((const float2*)embed_avg)[idx];
    float2 o;
    o.x = (ea.x * DECAYF + (1.0f - DECAYF) * es.x) * inv;
    o.y = (ea.y * DECAYF + (1.0f - DECAYF) * es.y) * inv;
    ((float2*)out_norm)[idx] = o;
}

extern "C" void kernel_launch(void* const* d_in, const int* in_sizes, int n_in,
                              void* d_out, int out_size, void* d_ws, size_t ws_size,
                              hipStream_t stream) {
    const float* x            = (const float*)d_in[0];
    const float* embed        = (const float*)d_in[1];
    const float* cluster_size = (const float*)d_in[2];
    const float* embed_avg    = (const float*)d_in[3];

    float* out      = (float*)d_out;
    float* out_q    = out;                               // 4194304
    float* out_ind  = out + 4194304;                     // 32768
    float* out_loss = out_ind + 32768;                   // 1
    float* out_cs   = out_loss + 1;                      // 4096
    float* out_norm = out_cs + 4096;                     // 524288

    // workspace layout (bytes). estg (2,113,536) and esum (2,097,152) ALIAS:
    // estg dead after argmax; esum zeroed after reorder launch.
    char* ws = (char*)d_ws;
    char*  estg = ws;                                    // 2,113,536
    float* esum = (float*)ws;                            // 2,097,152 (aliased)
    int*   ind  = (int*)(ws + 2113536);                  // 131,072
    int*   offsets = (int*)(ws + 2244608);               // 16,384
    int*   cursor  = (int*)(ws + 2260992);               // 16,384
    int*   rowids  = (int*)(ws + 2277376);               // 131,072
    int*   codesorted = (int*)(ws + 2408448);            // 131,072
    float* loss = (float*)(ws + 2539520);                // 4 (pad to 256)
    float* ntot = loss + 1;
    int*   bins = (int*)(ws + 2539776);                  // 16,384

    // zero loss/pad + bins (contiguous) before argmax
    hipMemsetAsync(ws + 2539520, 0, 256 + 16384, stream);

    esplit_kernel<<<KCODES / 4, 256, 0, stream>>>(embed, estg);
    argmax_kernel<<<NROWS / 128, 512, 0, stream>>>(x, estg, ind, out_ind,
                                                   bins, loss);
    scan_kernel<<<1, 1024, 0, stream>>>(bins, cluster_size, loss, offsets, cursor,
                                        out_cs, ntot, out_loss);
    reorder_kernel<<<NROWS / 256, 256, 0, stream>>>(ind, cursor, rowids, codesorted);
    // estg region is dead now; zero it for use as esum (stream-ordered)
    hipMemsetAsync(ws, 0, 2097152, stream);
    segred_kernel<<<NROWS / WROWS / 4, 256, 0, stream>>>(x, embed, rowids, codesorted,
                                                         offsets, bins, esum, out_q);
    norm_kernel<<<KCODES * DIM / 2 / 256, 256, 0, stream>>>(esum, embed_avg, out_cs,
                                                            ntot, out_norm);
}

// Round 5
// 192.484 us; speedup vs baseline: 1.3634x; 1.1626x over previous
//
#include <hip/hip_runtime.h>

#define NROWS 32768
#define DIM   128
#define KCODES 4096
#define DECAYF 0.8f
#define EPSF 1e-5f
#define COMMITW 0.25f

typedef _Float16 half8 __attribute__((ext_vector_type(8)));
typedef _Float16 half2v __attribute__((ext_vector_type(2)));
typedef float float4v __attribute__((ext_vector_type(4)));

// ---------------- embed -> staged split planes + e2 (+ zero bins/loss) -----
// estg layout (halves): [chunk][slice][code6][8], slice = pl*16 + ks*4 + q.
// Exactly MFMA B-fragment order -> direct coalesced register loads.
// R5: also zeroes bins[] and loss (runs before argmax in stream order),
// replacing a hipMemsetAsync dispatch.
__global__ __launch_bounds__(256) void esplit_kernel(const float* __restrict__ embed,
                                                     _Float16* __restrict__ estg,
                                                     float* __restrict__ e2h,
                                                     int* __restrict__ bins,
                                                     float* __restrict__ loss) {
    int code = blockIdx.x * 4 + (threadIdx.x >> 6);
    int lane = threadIdx.x & 63;
    float2 v = ((const float2*)(embed + (size_t)code * DIM))[lane];
    float s = v.x * v.x + v.y * v.y;
    #pragma unroll
    for (int off = 32; off > 0; off >>= 1) s += __shfl_down(s, off, 64);
    if (lane == 0) e2h[code] = 0.5f * s;
    if (lane == 1) bins[code] = 0;
    if (code == 0 && lane == 2) *loss = 0.f;

    int d = lane * 2;
    int ks = d >> 5, q = (d >> 3) & 3, j = d & 7;
    _Float16 h0 = (_Float16)v.x, l0 = (_Float16)(v.x - (float)h0);
    _Float16 h1 = (_Float16)v.y, l1 = (_Float16)(v.y - (float)h1);
    int chunk = code >> 6, c6 = code & 63;
    size_t base = (size_t)chunk * 16384;
    size_t hidx = base + (size_t)(( 0 + ks * 4 + q) * 64 + c6) * 8 + j;
    size_t lidx = base + (size_t)((16 + ks * 4 + q) * 64 + c6) * 8 + j;
    *(half2v*)&estg[hidx] = (half2v){h0, h1};
    *(half2v*)&estg[lidx] = (half2v){l0, l1};
}

// ---------------- MFMA argmax: 128 rows/block, barrier-free K-loop ---------
// score = x.e - 0.5|e|^2 (folded into acc init). fp16 2-way split, 3 products.
// 512 thr / 8 waves: wave w -> code-tile j=w&3, row-half rh=w>>2 (64 rows
// A-resident = 128 VGPRs/wave). Waves j and j+4 read the SAME B-frags
// ~concurrently -> L1/L2 line sharing. Register dbuf, no per-chunk barriers.
// R5: + s_setprio(1) around the MFMA clusters (T5; waves here are unsynced,
// the regime where setprio measured positive).
__global__ __launch_bounds__(512, 2) void argmax_kernel(const float* __restrict__ x,
                                                        const _Float16* __restrict__ estg,
                                                        const float* __restrict__ e2h,
                                                        int* __restrict__ ind,
                                                        float* __restrict__ out_ind,
                                                        int* __restrict__ bins,
                                                        float* __restrict__ loss) {
    __shared__ float rv[8][64];
    __shared__ int   ri[8][64];
    __shared__ float x2s[128];

    int tid = threadIdx.x;
    int lane = tid & 63;
    int w = tid >> 6;
    int j = w & 3;
    int rh = w >> 2;
    int m15 = lane & 15;
    int q = (lane >> 4) & 3;
    int n0 = blockIdx.x * 128;

    // A frags for this wave's 64 rows (rows n0 + rh*64 + rt*16 + m15)
    half8 Ah[4][4], Al[4][4];
    float xsq[4];
    #pragma unroll
    for (int rt = 0; rt < 4; ++rt) {
        xsq[rt] = 0.f;
        #pragma unroll
        for (int ks = 0; ks < 4; ++ks) {
            const float* p = x + (size_t)(n0 + rh * 64 + rt * 16 + m15) * DIM + ks * 32 + q * 8;
            float4 a = *(const float4*)p;
            float4 b = *(const float4*)(p + 4);
            float f[8] = {a.x, a.y, a.z, a.w, b.x, b.y, b.z, b.w};
            half8 H, L;
            #pragma unroll
            for (int e = 0; e < 8; ++e) {
                _Float16 h = (_Float16)f[e];
                H[e] = h;
                L[e] = (_Float16)(f[e] - (float)h);
                xsq[rt] += f[e] * f[e];
            }
            Ah[rt][ks] = H;
            Al[rt][ks] = L;
        }
        xsq[rt] += __shfl_xor(xsq[rt], 16, 64);
        xsq[rt] += __shfl_xor(xsq[rt], 32, 64);
    }
    if (j == 0 && lane < 16) {
        #pragma unroll
        for (int rt = 0; rt < 4; ++rt) x2s[rh * 64 + rt * 16 + m15] = xsq[rt];
    }

    float best[4][4];
    int   bidx[4][4];
    #pragma unroll
    for (int rt = 0; rt < 4; ++rt)
        #pragma unroll
        for (int r = 0; r < 4; ++r) { best[rt][r] = -3.0e38f; bidx[rt][r] = 0; }

    // B fragment base for this wave/lane within a chunk
    const _Float16* bbase = estg + (size_t)(j * 16 + m15) * 8 + (size_t)q * 512;
    const int cm = j * 16 + m15;

    half8 B0h[4], B0l[4], B1h[4], B1l[4];
    float e20, e21;

    // prefetch chunk 0 -> buf0
    {
        const _Float16* cb = bbase;
        #pragma unroll
        for (int ks = 0; ks < 4; ++ks) {
            B0h[ks] = *(const half8*)(cb + ks * 2048);
            B0l[ks] = *(const half8*)(cb + 8192 + ks * 2048);
        }
        e20 = e2h[cm];
    }

    #pragma unroll 1
    for (int ch = 0; ch < 64; ch += 2) {
        // prefetch ch+1 -> buf1
        {
            const _Float16* cb = bbase + (size_t)(ch + 1) * 16384;
            #pragma unroll
            for (int ks = 0; ks < 4; ++ks) {
                B1h[ks] = *(const half8*)(cb + ks * 2048);
                B1l[ks] = *(const half8*)(cb + 8192 + ks * 2048);
            }
            e21 = e2h[(ch + 1) * 64 + cm];
        }
        // compute ch from buf0 (acc init = -e2 folds the bias in)
        {
            float4v acc[4];
            #pragma unroll
            for (int rt = 0; rt < 4; ++rt) acc[rt] = (float4v){-e20, -e20, -e20, -e20};
            __builtin_amdgcn_s_setprio(1);
            #pragma unroll
            for (int ks = 0; ks < 4; ++ks)
                #pragma unroll
                for (int rt = 0; rt < 4; ++rt) {
                    acc[rt] = __builtin_amdgcn_mfma_f32_16x16x32_f16(Ah[rt][ks], B0h[ks], acc[rt], 0, 0, 0);
                    acc[rt] = __builtin_amdgcn_mfma_f32_16x16x32_f16(Al[rt][ks], B0h[ks], acc[rt], 0, 0, 0);
                    acc[rt] = __builtin_amdgcn_mfma_f32_16x16x32_f16(Ah[rt][ks], B0l[ks], acc[rt], 0, 0, 0);
                }
            __builtin_amdgcn_s_setprio(0);
            int c = ch * 64 + cm;
            #pragma unroll
            for (int rt = 0; rt < 4; ++rt)
                #pragma unroll
                for (int r = 0; r < 4; ++r) {
                    float s = acc[rt][r];
                    if (s > best[rt][r]) { best[rt][r] = s; bidx[rt][r] = c; }
                }
        }
        // prefetch ch+2 -> buf0
        if (ch + 2 < 64) {
            const _Float16* cb = bbase + (size_t)(ch + 2) * 16384;
            #pragma unroll
            for (int ks = 0; ks < 4; ++ks) {
                B0h[ks] = *(const half8*)(cb + ks * 2048);
                B0l[ks] = *(const half8*)(cb + 8192 + ks * 2048);
            }
            e20 = e2h[(ch + 2) * 64 + cm];
        }
        // compute ch+1 from buf1
        {
            float4v acc[4];
            #pragma unroll
            for (int rt = 0; rt < 4; ++rt) acc[rt] = (float4v){-e21, -e21, -e21, -e21};
            __builtin_amdgcn_s_setprio(1);
            #pragma unroll
            for (int ks = 0; ks < 4; ++ks)
                #pragma unroll
                for (int rt = 0; rt < 4; ++rt) {
                    acc[rt] = __builtin_amdgcn_mfma_f32_16x16x32_f16(Ah[rt][ks], B1h[ks], acc[rt], 0, 0, 0);
                    acc[rt] = __builtin_amdgcn_mfma_f32_16x16x32_f16(Al[rt][ks], B1h[ks], acc[rt], 0, 0, 0);
                    acc[rt] = __builtin_amdgcn_mfma_f32_16x16x32_f16(Ah[rt][ks], B1l[ks], acc[rt], 0, 0, 0);
                }
            __builtin_amdgcn_s_setprio(0);
            int c = (ch + 1) * 64 + cm;
            #pragma unroll
            for (int rt = 0; rt < 4; ++rt)
                #pragma unroll
                for (int r = 0; r < 4; ++r) {
                    float s = acc[rt][r];
                    if (s > best[rt][r]) { best[rt][r] = s; bidx[rt][r] = c; }
                }
        }
    }

    // reduce across the 16 code-lanes (m15); min index on ties
    #pragma unroll
    for (int rt = 0; rt < 4; ++rt)
        #pragma unroll
        for (int r = 0; r < 4; ++r) {
            float bv = best[rt][r];
            int   bi = bidx[rt][r];
            #pragma unroll
            for (int m = 1; m <= 8; m <<= 1) {
                float ov = __shfl_xor(bv, m, 64);
                int   oi = __shfl_xor(bi, m, 64);
                if (ov > bv || (ov == bv && oi < bi)) { bv = ov; bi = oi; }
            }
            if (m15 == 0) {
                int rl = rt * 16 + q * 4 + r;
                rv[w][rl] = bv;
                ri[w][rl] = bi;
            }
        }
    __syncthreads();
    if (tid < 128) {
        int rhh = tid >> 6;
        int rl  = tid & 63;
        float bv = rv[rhh * 4][rl];
        int   bi = ri[rhh * 4][rl];
        #pragma unroll
        for (int jj = 1; jj < 4; ++jj) {
            float ov = rv[rhh * 4 + jj][rl];
            int   oi = ri[rhh * 4 + jj][rl];
            if (ov > bv || (ov == bv && oi < bi)) { bv = ov; bi = oi; }
        }
        ind[n0 + tid] = bi;
        out_ind[n0 + tid] = (float)bi;
        atomicAdd(&bins[bi], 1);
        // commit-loss partial: |x - e_k|^2 = |x|^2 - 2*best_score
        float lp = x2s[tid] - 2.0f * bv;
        #pragma unroll
        for (int off = 32; off > 0; off >>= 1) lp += __shfl_down(lp, off, 64);
        if ((tid & 63) == 0) atomicAdd(loss, lp);
    }
}

// ---------------- scan: shuffle-based, 2 barriers ----------------
__global__ __launch_bounds__(1024) void scan_kernel(const int* __restrict__ bins,
                                                    const float* __restrict__ cluster_size,
                                                    const float* __restrict__ loss,
                                                    int* __restrict__ offsets,
                                                    int* __restrict__ cursor,
                                                    float* __restrict__ out_cs,
                                                    float* __restrict__ ntot,
                                                    float* __restrict__ out_loss) {
    __shared__ int   wtot[16];
    __shared__ float fred[16];
    int t = threadIdx.x;
    int lane = t & 63, wv = t >> 6;
    int b[4];
    float cs[4];
    float csum = 0.f;
    int s = 0;
    #pragma unroll
    for (int e = 0; e < 4; ++e) {
        b[e] = bins[t * 4 + e];
        s += b[e];
        cs[e] = cluster_size[t * 4 + e] * DECAYF + (1.0f - DECAYF) * (float)b[e];
        csum += cs[e];
    }
    int sc = s;
    #pragma unroll
    for (int off = 1; off < 64; off <<= 1) {
        int v = __shfl_up(sc, off, 64);
        if (lane >= off) sc += v;
    }
    float fc = csum;
    #pragma unroll
    for (int off = 32; off > 0; off >>= 1) fc += __shfl_down(fc, off, 64);
    if (lane == 63) wtot[wv] = sc;
    if (lane == 0) fred[wv] = fc;
    __syncthreads();
    if (t < 16) {
        int v = wtot[t];
        int scv = v;
        #pragma unroll
        for (int off = 1; off < 16; off <<= 1) {
            int u = __shfl_up(scv, off, 64);
            if (t >= off) scv += u;
        }
        wtot[t] = scv - v;
    }
    if (t == 0) {
        float tot = 0.f;
        #pragma unroll
        for (int i = 0; i < 16; ++i) tot += fred[i];
        *ntot = tot;
        *out_loss = COMMITW * (*loss) / (float)((size_t)NROWS * DIM);
    }
    __syncthreads();
    int ex = sc - s + wtot[wv];
    #pragma unroll
    for (int e = 0; e < 4; ++e) {
        offsets[t * 4 + e] = ex;
        cursor[t * 4 + e] = ex;
        out_cs[t * 4 + e] = cs[e];
        ex += b[e];
    }
}

// ---------------- reorder rows by code (also zero esum) --------------------
// R5: esum zeroing moved here from a hipMemsetAsync (runs before segred in
// stream order). 32768 threads x 64B = 2MB exactly.
__global__ __launch_bounds__(256) void reorder_kernel(const int* __restrict__ ind,
                                                      int* __restrict__ cursor,
                                                      int* __restrict__ rowids,
                                                      int* __restrict__ codesorted,
                                                      float* __restrict__ esum) {
    int row = blockIdx.x * 256 + threadIdx.x;
    float4 z = {0.f, 0.f, 0.f, 0.f};
    float4* ep = (float4*)(esum + (size_t)row * 16);
    #pragma unroll
    for (int i = 0; i < 4; ++i) ep[i] = z;
    int k = ind[row];
    int pos = atomicAdd(&cursor[k], 1);
    rowids[pos] = row;
    codesorted[pos] = k;
}

// ---------------- segmented esum + out_q: fixed 16-row windows -------------
#define WROWS 16
__global__ __launch_bounds__(256) void segred_kernel(const float* __restrict__ x,
                                                     const float* __restrict__ embed,
                                                     const int* __restrict__ rowids,
                                                     const int* __restrict__ codesorted,
                                                     const int* __restrict__ offsets,
                                                     const int* __restrict__ bins,
                                                     float* __restrict__ esum,
                                                     float* __restrict__ out_q) {
    int tid = threadIdx.x;
    int lane = tid & 63;
    int wv = blockIdx.x * 4 + (tid >> 6);
    int w0 = wv * WROWS;

    int i16 = lane & (WROWS - 1);
    int rowv = rowids[w0 + i16];
    int kv   = codesorted[w0 + i16];

    float2 xv[WROWS];
    #pragma unroll
    for (int i = 0; i < WROWS; ++i) {
        int row = __shfl(rowv, i, 64);
        xv[i] = ((const float2*)(x + (size_t)row * DIM))[lane];
    }

    int curk = __shfl(kv, 0, 64);
    float2 qv = ((const float2*)(embed + (size_t)curk * DIM))[lane];
    float2 acc = {0.f, 0.f};

    #pragma unroll
    for (int i = 0; i < WROWS; ++i) {
        int row = __shfl(rowv, i, 64);
        int k   = __shfl(kv, i, 64);
        if (k != curk) {
            int sbeg = offsets[curk];
            int send = sbeg + bins[curk];
            float* ep = esum + (size_t)curk * DIM + lane * 2;
            if (sbeg >= w0 && send <= w0 + WROWS) {
                *(float2*)ep = acc;
            } else {
                atomicAdd(ep, acc.x);
                atomicAdd(ep + 1, acc.y);
            }
            curk = k;
            acc = (float2){0.f, 0.f};
            qv = ((const float2*)(embed + (size_t)curk * DIM))[lane];
        }
        acc.x += xv[i].x;
        acc.y += xv[i].y;
        ((float2*)(out_q + (size_t)row * DIM))[lane] = qv;
    }
    {
        int sbeg = offsets[curk];
        int send = sbeg + bins[curk];
        float* ep = esum + (size_t)curk * DIM + lane * 2;
        if (sbeg >= w0 && send <= w0 + WROWS) {
            *(float2*)ep = acc;
        } else {
            atomicAdd(ep, acc.x);
            atomicAdd(ep + 1, acc.y);
        }
    }
}

// ---------------- norm: out_norm from esum (streaming) ----------------
__global__ __launch_bounds__(256) void norm_kernel(const float* __restrict__ esum,
                                                   const float* __restrict__ embed_avg,
                                                   const float* __restrict__ out_cs,
                                                   const float* __restrict__ ntot,
                                                   float* __restrict__ out_norm) {
    int idx = blockIdx.x * 256 + threadIdx.x;
    int k = idx >> 6;
    float nt = *ntot;
    float cs = out_cs[k];
    float cluster = (cs + EPSF) / (nt + (float)KCODES * EPSF) * nt;
    float inv = 1.0f / cluster;
    float2 es = ((const float2*)esum)[idx];
    float2 ea = ((const float2*)embed_avg)[idx];
    float2 o;
    o.x = (ea.x * DECAYF + (1.0f - DECAYF) * es.x) * inv;
    o.y = (ea.y * DECAYF + (1.0f - DECAYF) * es.y) * inv;
    ((float2*)out_norm)[idx] = o;
}

extern "C" void kernel_launch(void* const* d_in, const int* in_sizes, int n_in,
                              void* d_out, int out_size, void* d_ws, size_t ws_size,
                              hipStream_t stream) {
    const float* x            = (const float*)d_in[0];
    const float* embed        = (const float*)d_in[1];
    const float* cluster_size = (const float*)d_in[2];
    const float* embed_avg    = (const float*)d_in[3];

    float* out      = (float*)d_out;
    float* out_q    = out;                               // 4194304
    float* out_ind  = out + 4194304;                     // 32768
    float* out_loss = out_ind + 32768;                   // 1
    float* out_cs   = out_loss + 1;                      // 4096
    float* out_norm = out_cs + 4096;                     // 524288

    // workspace layout (bytes)
    char* ws = (char*)d_ws;
    _Float16* estg = (_Float16*)ws;                      // 2,097,152
    float* e2h   = (float*)(ws + 2097152);               // 16,384
    int*   ind   = (int*)(ws + 2113536);                 // 131,072
    int*   offsets = (int*)(ws + 2244608);               // 16,384
    int*   cursor  = (int*)(ws + 2260992);               // 16,384
    int*   rowids  = (int*)(ws + 2277376);               // 131,072
    int*   codesorted = (int*)(ws + 2408448);            // 131,072
    float* loss  = (float*)(ws + 2539520);               // 4 (pad to 256)
    float* ntot  = loss + 1;
    int*   bins  = (int*)(ws + 2539776);                 // 16,384
    float* esum  = (float*)(ws + 2556160);               // 2,097,152

    // no memsets: esplit zeroes bins+loss; reorder zeroes esum (stream order)
    esplit_kernel<<<KCODES / 4, 256, 0, stream>>>(embed, estg, e2h, bins, loss);
    argmax_kernel<<<NROWS / 128, 512, 0, stream>>>(x, estg, e2h, ind, out_ind,
                                                   bins, loss);
    scan_kernel<<<1, 1024, 0, stream>>>(bins, cluster_size, loss, offsets, cursor,
                                        out_cs, ntot, out_loss);
    reorder_kernel<<<NROWS / 256, 256, 0, stream>>>(ind, cursor, rowids, codesorted,
                                                    esum);
    segred_kernel<<<NROWS / WROWS / 4, 256, 0, stream>>>(x, embed, rowids, codesorted,
                                                         offsets, bins, esum, out_q);
    norm_kernel<<<KCODES * DIM / 2 / 256, 256, 0, stream>>>(esum, embed_avg, out_cs,
                                                            ntot, out_norm);
}

// Round 6
// 191.733 us; speedup vs baseline: 1.3687x; 1.0039x over previous
//
#include <hip/hip_runtime.h>

#define NROWS 32768
#define DIM   128
#define KCODES 4096
#define DECAYF 0.8f
#define EPSF 1e-5f
#define COMMITW 0.25f

typedef _Float16 half8 __attribute__((ext_vector_type(8)));
typedef _Float16 half2v __attribute__((ext_vector_type(2)));
typedef float float4v __attribute__((ext_vector_type(4)));

// ---------------- embed -> staged split planes + e2 (+ zero bins/loss) -----
// estg layout (halves): [chunk][slice][code6][8], slice = pl*16 + ks*4 + q.
// Exactly MFMA B-fragment order -> direct coalesced register loads.
__global__ __launch_bounds__(256) void esplit_kernel(const float* __restrict__ embed,
                                                     _Float16* __restrict__ estg,
                                                     float* __restrict__ e2h,
                                                     int* __restrict__ bins,
                                                     float* __restrict__ loss) {
    int code = blockIdx.x * 4 + (threadIdx.x >> 6);
    int lane = threadIdx.x & 63;
    float2 v = ((const float2*)(embed + (size_t)code * DIM))[lane];
    float s = v.x * v.x + v.y * v.y;
    #pragma unroll
    for (int off = 32; off > 0; off >>= 1) s += __shfl_down(s, off, 64);
    if (lane == 0) e2h[code] = 0.5f * s;
    if (lane == 1) bins[code] = 0;
    if (code == 0 && lane == 2) *loss = 0.f;

    int d = lane * 2;
    int ks = d >> 5, q = (d >> 3) & 3, j = d & 7;
    _Float16 h0 = (_Float16)v.x, l0 = (_Float16)(v.x - (float)h0);
    _Float16 h1 = (_Float16)v.y, l1 = (_Float16)(v.y - (float)h1);
    int chunk = code >> 6, c6 = code & 63;
    size_t base = (size_t)chunk * 16384;
    size_t hidx = base + (size_t)(( 0 + ks * 4 + q) * 64 + c6) * 8 + j;
    size_t lidx = base + (size_t)((16 + ks * 4 + q) * 64 + c6) * 8 + j;
    *(half2v*)&estg[hidx] = (half2v){h0, h1};
    *(half2v*)&estg[lidx] = (half2v){l0, l1};
}

// ---------------- MFMA argmax: 128 rows/block, barrier-free K-loop ---------
// score = x.e - 0.5|e|^2 (folded into acc init). fp16 2-way split, 3 products.
// 512 thr / 8 waves: wave w -> code-tile j=w&3, row-half rh=w>>2 (64 rows
// A-resident = 128 VGPRs/wave). Register dbuf, no per-chunk barriers.
// + s_setprio(1) around the MFMA clusters (T5; R5 measured +4%).
__global__ __launch_bounds__(512, 2) void argmax_kernel(const float* __restrict__ x,
                                                        const _Float16* __restrict__ estg,
                                                        const float* __restrict__ e2h,
                                                        int* __restrict__ ind,
                                                        float* __restrict__ out_ind,
                                                        int* __restrict__ bins,
                                                        float* __restrict__ loss) {
    __shared__ float rv[8][64];
    __shared__ int   ri[8][64];
    __shared__ float x2s[128];

    int tid = threadIdx.x;
    int lane = tid & 63;
    int w = tid >> 6;
    int j = w & 3;
    int rh = w >> 2;
    int m15 = lane & 15;
    int q = (lane >> 4) & 3;
    int n0 = blockIdx.x * 128;

    // A frags for this wave's 64 rows (rows n0 + rh*64 + rt*16 + m15)
    half8 Ah[4][4], Al[4][4];
    float xsq[4];
    #pragma unroll
    for (int rt = 0; rt < 4; ++rt) {
        xsq[rt] = 0.f;
        #pragma unroll
        for (int ks = 0; ks < 4; ++ks) {
            const float* p = x + (size_t)(n0 + rh * 64 + rt * 16 + m15) * DIM + ks * 32 + q * 8;
            float4 a = *(const float4*)p;
            float4 b = *(const float4*)(p + 4);
            float f[8] = {a.x, a.y, a.z, a.w, b.x, b.y, b.z, b.w};
            half8 H, L;
            #pragma unroll
            for (int e = 0; e < 8; ++e) {
                _Float16 h = (_Float16)f[e];
                H[e] = h;
                L[e] = (_Float16)(f[e] - (float)h);
                xsq[rt] += f[e] * f[e];
            }
            Ah[rt][ks] = H;
            Al[rt][ks] = L;
        }
        xsq[rt] += __shfl_xor(xsq[rt], 16, 64);
        xsq[rt] += __shfl_xor(xsq[rt], 32, 64);
    }
    if (j == 0 && lane < 16) {
        #pragma unroll
        for (int rt = 0; rt < 4; ++rt) x2s[rh * 64 + rt * 16 + m15] = xsq[rt];
    }

    float best[4][4];
    int   bidx[4][4];
    #pragma unroll
    for (int rt = 0; rt < 4; ++rt)
        #pragma unroll
        for (int r = 0; r < 4; ++r) { best[rt][r] = -3.0e38f; bidx[rt][r] = 0; }

    // B fragment base for this wave/lane within a chunk
    const _Float16* bbase = estg + (size_t)(j * 16 + m15) * 8 + (size_t)q * 512;
    const int cm = j * 16 + m15;

    half8 B0h[4], B0l[4], B1h[4], B1l[4];
    float e20, e21;

    // prefetch chunk 0 -> buf0
    {
        const _Float16* cb = bbase;
        #pragma unroll
        for (int ks = 0; ks < 4; ++ks) {
            B0h[ks] = *(const half8*)(cb + ks * 2048);
            B0l[ks] = *(const half8*)(cb + 8192 + ks * 2048);
        }
        e20 = e2h[cm];
    }

    #pragma unroll 1
    for (int ch = 0; ch < 64; ch += 2) {
        // prefetch ch+1 -> buf1
        {
            const _Float16* cb = bbase + (size_t)(ch + 1) * 16384;
            #pragma unroll
            for (int ks = 0; ks < 4; ++ks) {
                B1h[ks] = *(const half8*)(cb + ks * 2048);
                B1l[ks] = *(const half8*)(cb + 8192 + ks * 2048);
            }
            e21 = e2h[(ch + 1) * 64 + cm];
        }
        // compute ch from buf0 (acc init = -e2 folds the bias in)
        {
            float4v acc[4];
            #pragma unroll
            for (int rt = 0; rt < 4; ++rt) acc[rt] = (float4v){-e20, -e20, -e20, -e20};
            __builtin_amdgcn_s_setprio(1);
            #pragma unroll
            for (int ks = 0; ks < 4; ++ks)
                #pragma unroll
                for (int rt = 0; rt < 4; ++rt) {
                    acc[rt] = __builtin_amdgcn_mfma_f32_16x16x32_f16(Ah[rt][ks], B0h[ks], acc[rt], 0, 0, 0);
                    acc[rt] = __builtin_amdgcn_mfma_f32_16x16x32_f16(Al[rt][ks], B0h[ks], acc[rt], 0, 0, 0);
                    acc[rt] = __builtin_amdgcn_mfma_f32_16x16x32_f16(Ah[rt][ks], B0l[ks], acc[rt], 0, 0, 0);
                }
            __builtin_amdgcn_s_setprio(0);
            int c = ch * 64 + cm;
            #pragma unroll
            for (int rt = 0; rt < 4; ++rt)
                #pragma unroll
                for (int r = 0; r < 4; ++r) {
                    float s = acc[rt][r];
                    if (s > best[rt][r]) { best[rt][r] = s; bidx[rt][r] = c; }
                }
        }
        // prefetch ch+2 -> buf0
        if (ch + 2 < 64) {
            const _Float16* cb = bbase + (size_t)(ch + 2) * 16384;
            #pragma unroll
            for (int ks = 0; ks < 4; ++ks) {
                B0h[ks] = *(const half8*)(cb + ks * 2048);
                B0l[ks] = *(const half8*)(cb + 8192 + ks * 2048);
            }
            e20 = e2h[(ch + 2) * 64 + cm];
        }
        // compute ch+1 from buf1
        {
            float4v acc[4];
            #pragma unroll
            for (int rt = 0; rt < 4; ++rt) acc[rt] = (float4v){-e21, -e21, -e21, -e21};
            __builtin_amdgcn_s_setprio(1);
            #pragma unroll
            for (int ks = 0; ks < 4; ++ks)
                #pragma unroll
                for (int rt = 0; rt < 4; ++rt) {
                    acc[rt] = __builtin_amdgcn_mfma_f32_16x16x32_f16(Ah[rt][ks], B1h[ks], acc[rt], 0, 0, 0);
                    acc[rt] = __builtin_amdgcn_mfma_f32_16x16x32_f16(Al[rt][ks], B1h[ks], acc[rt], 0, 0, 0);
                    acc[rt] = __builtin_amdgcn_mfma_f32_16x16x32_f16(Ah[rt][ks], B1l[ks], acc[rt], 0, 0, 0);
                }
            __builtin_amdgcn_s_setprio(0);
            int c = (ch + 1) * 64 + cm;
            #pragma unroll
            for (int rt = 0; rt < 4; ++rt)
                #pragma unroll
                for (int r = 0; r < 4; ++r) {
                    float s = acc[rt][r];
                    if (s > best[rt][r]) { best[rt][r] = s; bidx[rt][r] = c; }
                }
        }
    }

    // reduce across the 16 code-lanes (m15); min index on ties
    #pragma unroll
    for (int rt = 0; rt < 4; ++rt)
        #pragma unroll
        for (int r = 0; r < 4; ++r) {
            float bv = best[rt][r];
            int   bi = bidx[rt][r];
            #pragma unroll
            for (int m = 1; m <= 8; m <<= 1) {
                float ov = __shfl_xor(bv, m, 64);
                int   oi = __shfl_xor(bi, m, 64);
                if (ov > bv || (ov == bv && oi < bi)) { bv = ov; bi = oi; }
            }
            if (m15 == 0) {
                int rl = rt * 16 + q * 4 + r;
                rv[w][rl] = bv;
                ri[w][rl] = bi;
            }
        }
    __syncthreads();
    if (tid < 128) {
        int rhh = tid >> 6;
        int rl  = tid & 63;
        float bv = rv[rhh * 4][rl];
        int   bi = ri[rhh * 4][rl];
        #pragma unroll
        for (int jj = 1; jj < 4; ++jj) {
            float ov = rv[rhh * 4 + jj][rl];
            int   oi = ri[rhh * 4 + jj][rl];
            if (ov > bv || (ov == bv && oi < bi)) { bv = ov; bi = oi; }
        }
        ind[n0 + tid] = bi;
        out_ind[n0 + tid] = (float)bi;
        atomicAdd(&bins[bi], 1);
        // commit-loss partial: |x - e_k|^2 = |x|^2 - 2*best_score
        float lp = x2s[tid] - 2.0f * bv;
        #pragma unroll
        for (int off = 32; off > 0; off >>= 1) lp += __shfl_down(lp, off, 64);
        if ((tid & 63) == 0) atomicAdd(loss, lp);
    }
}

// ---------------- scan: shuffle-based, 2 barriers ----------------
__global__ __launch_bounds__(1024) void scan_kernel(const int* __restrict__ bins,
                                                    const float* __restrict__ cluster_size,
                                                    const float* __restrict__ loss,
                                                    int* __restrict__ offsets,
                                                    int* __restrict__ cursor,
                                                    float* __restrict__ out_cs,
                                                    float* __restrict__ ntot,
                                                    float* __restrict__ out_loss) {
    __shared__ int   wtot[16];
    __shared__ float fred[16];
    int t = threadIdx.x;
    int lane = t & 63, wv = t >> 6;
    int b[4];
    float cs[4];
    float csum = 0.f;
    int s = 0;
    #pragma unroll
    for (int e = 0; e < 4; ++e) {
        b[e] = bins[t * 4 + e];
        s += b[e];
        cs[e] = cluster_size[t * 4 + e] * DECAYF + (1.0f - DECAYF) * (float)b[e];
        csum += cs[e];
    }
    int sc = s;
    #pragma unroll
    for (int off = 1; off < 64; off <<= 1) {
        int v = __shfl_up(sc, off, 64);
        if (lane >= off) sc += v;
    }
    float fc = csum;
    #pragma unroll
    for (int off = 32; off > 0; off >>= 1) fc += __shfl_down(fc, off, 64);
    if (lane == 63) wtot[wv] = sc;
    if (lane == 0) fred[wv] = fc;
    __syncthreads();
    if (t < 16) {
        int v = wtot[t];
        int scv = v;
        #pragma unroll
        for (int off = 1; off < 16; off <<= 1) {
            int u = __shfl_up(scv, off, 64);
            if (t >= off) scv += u;
        }
        wtot[t] = scv - v;
    }
    if (t == 0) {
        float tot = 0.f;
        #pragma unroll
        for (int i = 0; i < 16; ++i) tot += fred[i];
        *ntot = tot;
        *out_loss = COMMITW * (*loss) / (float)((size_t)NROWS * DIM);
    }
    __syncthreads();
    int ex = sc - s + wtot[wv];
    #pragma unroll
    for (int e = 0; e < 4; ++e) {
        offsets[t * 4 + e] = ex;
        cursor[t * 4 + e] = ex;
        out_cs[t * 4 + e] = cs[e];
        ex += b[e];
    }
}

// ------- reorder + quantize-gather + zero esum (wave-per-4-rows) ----------
// R6: out_q gather moved HERE from segred. Each wave: 4 rows; lanes 0-3 do
// the cursor atomics/scatter, all 64 lanes gather embed[ind[row]] (512B,
// L2-resident) and store out_q — 4 independent gathers/wave, latency fully
// parallel, removing segred's serial qv-dependency chain.
__global__ __launch_bounds__(256) void reorder_kernel(const int* __restrict__ ind,
                                                      int* __restrict__ cursor,
                                                      int* __restrict__ rowids,
                                                      int* __restrict__ codesorted,
                                                      const float* __restrict__ embed,
                                                      float* __restrict__ out_q,
                                                      float* __restrict__ esum) {
    int tid = threadIdx.x;
    int lane = tid & 63;
    int wv = blockIdx.x * 4 + (tid >> 6);

    // zero esum: 2048 blocks x 256 threads = 524288 = KCODES*DIM floats
    esum[blockIdx.x * 256 + tid] = 0.f;

    if (lane < 4) {
        int row = wv * 4 + lane;
        int k = ind[row];
        int pos = atomicAdd(&cursor[k], 1);
        rowids[pos] = row;
        codesorted[pos] = k;
    }
    #pragma unroll
    for (int i = 0; i < 4; ++i) {
        int row = wv * 4 + i;
        int k = ind[row];   // wave-uniform broadcast load
        float2 qv = ((const float2*)(embed + (size_t)k * DIM))[lane];
        ((float2*)(out_q + (size_t)row * DIM))[lane] = qv;
    }
}

// ---------------- segmented esum: fixed 16-row windows (no out_q) ----------
#define WROWS 16
__global__ __launch_bounds__(256) void segred_kernel(const float* __restrict__ x,
                                                     const int* __restrict__ rowids,
                                                     const int* __restrict__ codesorted,
                                                     const int* __restrict__ offsets,
                                                     const int* __restrict__ bins,
                                                     float* __restrict__ esum) {
    int tid = threadIdx.x;
    int lane = tid & 63;
    int wv = blockIdx.x * 4 + (tid >> 6);
    int w0 = wv * WROWS;

    int i16 = lane & (WROWS - 1);
    int rowv = rowids[w0 + i16];
    int kv   = codesorted[w0 + i16];

    float2 xv[WROWS];
    #pragma unroll
    for (int i = 0; i < WROWS; ++i) {
        int row = __shfl(rowv, i, 64);
        xv[i] = ((const float2*)(x + (size_t)row * DIM))[lane];
    }

    int curk = __shfl(kv, 0, 64);
    float2 acc = {0.f, 0.f};

    #pragma unroll
    for (int i = 0; i < WROWS; ++i) {
        int k = __shfl(kv, i, 64);
        if (k != curk) {
            int sbeg = offsets[curk];
            int send = sbeg + bins[curk];
            float* ep = esum + (size_t)curk * DIM + lane * 2;
            if (sbeg >= w0 && send <= w0 + WROWS) {
                *(float2*)ep = acc;
            } else {
                atomicAdd(ep, acc.x);
                atomicAdd(ep + 1, acc.y);
            }
            curk = k;
            acc = (float2){0.f, 0.f};
        }
        acc.x += xv[i].x;
        acc.y += xv[i].y;
    }
    {
        int sbeg = offsets[curk];
        int send = sbeg + bins[curk];
        float* ep = esum + (size_t)curk * DIM + lane * 2;
        if (sbeg >= w0 && send <= w0 + WROWS) {
            *(float2*)ep = acc;
        } else {
            atomicAdd(ep, acc.x);
            atomicAdd(ep + 1, acc.y);
        }
    }
}

// ---------------- norm: out_norm from esum (streaming) ----------------
__global__ __launch_bounds__(256) void norm_kernel(const float* __restrict__ esum,
                                                   const float* __restrict__ embed_avg,
                                                   const float* __restrict__ out_cs,
                                                   const float* __restrict__ ntot,
                                                   float* __restrict__ out_norm) {
    int idx = blockIdx.x * 256 + threadIdx.x;
    int k = idx >> 6;
    float nt = *ntot;
    float cs = out_cs[k];
    float cluster = (cs + EPSF) / (nt + (float)KCODES * EPSF) * nt;
    float inv = 1.0f / cluster;
    float2 es = ((const float2*)esum)[idx];
    float2 ea = ((const float2*)embed_avg)[idx];
    float2 o;
    o.x = (ea.x * DECAYF + (1.0f - DECAYF) * es.x) * inv;
    o.y = (ea.y * DECAYF + (1.0f - DECAYF) * es.y) * inv;
    ((float2*)out_norm)[idx] = o;
}

extern "C" void kernel_launch(void* const* d_in, const int* in_sizes, int n_in,
                              void* d_out, int out_size, void* d_ws, size_t ws_size,
                              hipStream_t stream) {
    const float* x            = (const float*)d_in[0];
    const float* embed        = (const float*)d_in[1];
    const float* cluster_size = (const float*)d_in[2];
    const float* embed_avg    = (const float*)d_in[3];

    float* out      = (float*)d_out;
    float* out_q    = out;                               // 4194304
    float* out_ind  = out + 4194304;                     // 32768
    float* out_loss = out_ind + 32768;                   // 1
    float* out_cs   = out_loss + 1;                      // 4096
    float* out_norm = out_cs + 4096;                     // 524288

    // workspace layout (bytes)
    char* ws = (char*)d_ws;
    _Float16* estg = (_Float16*)ws;                      // 2,097,152
    float* e2h   = (float*)(ws + 2097152);               // 16,384
    int*   ind   = (int*)(ws + 2113536);                 // 131,072
    int*   offsets = (int*)(ws + 2244608);               // 16,384
    int*   cursor  = (int*)(ws + 2260992);               // 16,384
    int*   rowids  = (int*)(ws + 2277376);               // 131,072
    int*   codesorted = (int*)(ws + 2408448);            // 131,072
    float* loss  = (float*)(ws + 2539520);               // 4 (pad to 256)
    float* ntot  = loss + 1;
    int*   bins  = (int*)(ws + 2539776);                 // 16,384
    float* esum  = (float*)(ws + 2556160);               // 2,097,152

    // no memsets: esplit zeroes bins+loss; reorder zeroes esum (stream order)
    esplit_kernel<<<KCODES / 4, 256, 0, stream>>>(embed, estg, e2h, bins, loss);
    argmax_kernel<<<NROWS / 128, 512, 0, stream>>>(x, estg, e2h, ind, out_ind,
                                                   bins, loss);
    scan_kernel<<<1, 1024, 0, stream>>>(bins, cluster_size, loss, offsets, cursor,
                                        out_cs, ntot, out_loss);
    reorder_kernel<<<NROWS / 16, 256, 0, stream>>>(ind, cursor, rowids, codesorted,
                                                   embed, out_q, esum);
    segred_kernel<<<NROWS / WROWS / 4, 256, 0, stream>>>(x, rowids, codesorted,
                                                         offsets, bins, esum);
    norm_kernel<<<KCODES * DIM / 2 / 256, 256, 0, stream>>>(esum, embed_avg, out_cs,
                                                            ntot, out_norm);
}